// Round 1
// baseline (192700.024 us; speedup 1.0000x reference)
//
#include <hip/hip_runtime.h>
#include <math.h>
#include <stdint.h>

#define SEQ  4096
#define HB   1536   // big hidden (e1, d2)
#define HS   768    // small hidden (e2, d1)
#define NWG  256
#define NTHR 512

// ws layout in 4-byte units
#define WS_FLAGS 0
#define WS_H1    256
#define WS_H2    (WS_H1  + 4*HB)
#define WS_HD1   (WS_H2  + 4*HS)
#define WS_HD2   (WS_HD1 + 4*HS)
#define WS_OUTP  (WS_HD2 + 4*HB)

__device__ __forceinline__ float sigf(float x){ return 1.0f/(1.0f+expf(-x)); }

__device__ __forceinline__ float wsum64(float v){
#pragma unroll
  for (int m = 32; m > 0; m >>= 1) v += __shfl_xor(v, m);
  return v;
}

__global__ void init_ws(float* ws){
  int i = threadIdx.x + blockIdx.x*blockDim.x;
  const int n = WS_OUTP;     // flags + all 4 h rings
  for (; i < n; i += blockDim.x*gridDim.x) ws[i] = 0.0f;
}

__device__ __forceinline__ void gridbar(int* flags, int step, int tid, int w){
  __syncthreads();   // all WG stores issued & drained (vmcnt) before release
  if (tid == 0)
    __hip_atomic_store(&flags[w], step, __ATOMIC_RELEASE, __HIP_MEMORY_SCOPE_AGENT);
  if (tid < 64){
    const int b = tid*4;
    for(;;){
      int f0 = __hip_atomic_load(&flags[b+0], __ATOMIC_RELAXED, __HIP_MEMORY_SCOPE_AGENT);
      int f1 = __hip_atomic_load(&flags[b+1], __ATOMIC_RELAXED, __HIP_MEMORY_SCOPE_AGENT);
      int f2 = __hip_atomic_load(&flags[b+2], __ATOMIC_RELAXED, __HIP_MEMORY_SCOPE_AGENT);
      int f3 = __hip_atomic_load(&flags[b+3], __ATOMIC_RELAXED, __HIP_MEMORY_SCOPE_AGENT);
      if (__all(f0 >= step && f1 >= step && f2 >= step && f3 >= step)) break;
    }
  }
  __syncthreads();
  __builtin_amdgcn_fence(__ATOMIC_ACQUIRE, "agent");  // every thread: inv L1/L2 after flags confirmed
}

__global__ __launch_bounds__(NTHR, 2) void lstm_ae(
    const float* __restrict__ x,
    const float* __restrict__ e1Wih, const float* __restrict__ e1Whh,
    const float* __restrict__ e1bih, const float* __restrict__ e1bhh,
    const float* __restrict__ e2Wih, const float* __restrict__ e2Whh,
    const float* __restrict__ e2bih, const float* __restrict__ e2bhh,
    const float* __restrict__ d1Wih, const float* __restrict__ d1Whh,
    const float* __restrict__ d1bih, const float* __restrict__ d1bhh,
    const float* __restrict__ d2Wih, const float* __restrict__ d2Whh,
    const float* __restrict__ d2bih, const float* __restrict__ d2bhh,
    const float* __restrict__ outW, const float* __restrict__ outb,
    float* __restrict__ out, float* __restrict__ ws)
{
  const int w    = blockIdx.x;
  const int tid  = threadIdx.x;
  const int lane = tid & 63;
  const int wv   = tid >> 6;          // wave 0..7

  int*   flags = (int*)ws;
  float* h1r  = ws + WS_H1;
  float* h2r  = ws + WS_H2;
  float* hd1r = ws + WS_HD1;
  float* hd2r = ws + WS_HD2;
  float* outp = ws + WS_OUTP;

  __shared__ float lx[SEQ];           // 16 KB: whole input signal
  __shared__ float lhB[HB];           // staged big h (h1 / hd2)
  __shared__ float lhS[HS];           // staged small h (h2 / hd1)
  __shared__ float lgB[24], lgS[12];  // reduced gate pre-activations
  __shared__ float lcB[6],  lcS[3];   // cell states (6 big units, 3 small units per WG)
  __shared__ float lzw[12], lowv[6], lops[6];

  for (int i = tid; i < SEQ; i += NTHR) lx[i] = x[i];

  // ---- row index mapping ----
  // big (4H=6144): WG owns units 6w..6w+5; local row lr = q*6+u; wave wv does lr=3wv..3wv+2
  int Rb[3];
#pragma unroll
  for (int r = 0; r < 3; ++r){
    int lr = 3*wv + r;
    Rb[r] = (lr/6)*HB + 6*w + (lr%6);
  }
  // small (4H=3072): WG owns units 3w..3w+2; local row lr2 = q*3+u; wave wv does lr2=wv and 8+wv (wv<4)
  const int lrA = wv, lrB = 8 + wv;
  const int RsA = (lrA/3)*HS + 3*w + (lrA%3);
  const int RsB = (lrB/3)*HS + 3*w + (lrB%3);

  // ---- EN-phase weights into registers ----
  float wR[3][24];   // e1_Whh rows (K=1536, cols k*64+lane)     later: d2_Whh
  float wI[48];      // e2_Wih rows A/B (K=1536)                 later: d2_Wih [3][12]
  float wS[2][12];   // e2_Whh rows A/B (K=768)                  later: d1_Wih, then d1_Whh
#pragma unroll
  for (int r = 0; r < 3; ++r){
    const float* src = e1Whh + (size_t)Rb[r]*HB + lane;
#pragma unroll
    for (int k = 0; k < 24; ++k) wR[r][k] = src[(size_t)k*64];
  }
  {
    const float* sA = e2Wih + (size_t)RsA*HB + lane;
#pragma unroll
    for (int k = 0; k < 24; ++k) wI[k] = sA[(size_t)k*64];
    const float* hA = e2Whh + (size_t)RsA*HS + lane;
#pragma unroll
    for (int k = 0; k < 12; ++k) wS[0][k] = hA[(size_t)k*64];
    if (wv < 4){
      const float* sB = e2Wih + (size_t)RsB*HB + lane;
#pragma unroll
      for (int k = 0; k < 24; ++k) wI[24+k] = sB[(size_t)k*64];
      const float* hBp = e2Whh + (size_t)RsB*HS + lane;
#pragma unroll
      for (int k = 0; k < 12; ++k) wS[1][k] = hBp[(size_t)k*64];
    }
  }
  float wihB[3], biasB[3], biasS0, biasS1;
#pragma unroll
  for (int r = 0; r < 3; ++r){
    wihB[r]  = e1Wih[Rb[r]];
    biasB[r] = e1bih[Rb[r]] + e1bhh[Rb[r]];
  }
  biasS0 = e2bih[RsA] + e2bhh[RsA];
  biasS1 = (wv < 4) ? (e2bih[RsB] + e2bhh[RsB]) : 0.0f;

  if (tid < 6)              lcB[tid]   = 0.0f;   // same thread writes & later reads: no sync needed
  if (tid >= 8 && tid < 11) lcS[tid-8] = 0.0f;

  int step = 0;

  // ================= Phase EN: e1 step t  ||  e2 step t-1 =================
  for (int t = 0; t <= SEQ; ++t){
    if (tid < 384)
      ((float4*)lhB)[tid] = ((const float4*)(h1r + (size_t)(t&3)*HB))[tid];
    if (t >= 1 && tid >= 384){
      int i = tid - 384;
      const float4* s4 = (const float4*)(h2r + (size_t)((t-1)&3)*HS);
      ((float4*)lhS)[i] = s4[i];
      if (i < 64) ((float4*)lhS)[128+i] = s4[128+i];
    }
    __syncthreads();

    float hB[24];
#pragma unroll
    for (int k = 0; k < 24; ++k) hB[k] = lhB[k*64 + lane];

    if (t < SEQ){   // e1 step t: gates = Whh@h1[t-1] + Wih*x[t] + bias
      float a0=0.f, a1=0.f, a2=0.f;
#pragma unroll
      for (int k = 0; k < 24; ++k){
        a0 += wR[0][k]*hB[k];
        a1 += wR[1][k]*hB[k];
        a2 += wR[2][k]*hB[k];
      }
      a0 = wsum64(a0); a1 = wsum64(a1); a2 = wsum64(a2);
      if (lane == 0){
        float xt = lx[t];
        lgB[3*wv+0] = a0 + wihB[0]*xt + biasB[0];
        lgB[3*wv+1] = a1 + wihB[1]*xt + biasB[1];
        lgB[3*wv+2] = a2 + wihB[2]*xt + biasB[2];
      }
    }
    if (t >= 1){    // e2 step t-1: gates = Wih@h1[t-1] + Whh@h2[t-2] + bias
      float hS[12];
#pragma unroll
      for (int k = 0; k < 12; ++k) hS[k] = lhS[k*64 + lane];
      float b0 = 0.f;
#pragma unroll
      for (int k = 0; k < 24; ++k) b0 += wI[k]*hB[k];
#pragma unroll
      for (int k = 0; k < 12; ++k) b0 += wS[0][k]*hS[k];
      b0 = wsum64(b0);
      if (lane == 0) lgS[lrA] = b0 + biasS0;
      if (wv < 4){
        float b1 = 0.f;
#pragma unroll
        for (int k = 0; k < 24; ++k) b1 += wI[24+k]*hB[k];
#pragma unroll
        for (int k = 0; k < 12; ++k) b1 += wS[1][k]*hS[k];
        b1 = wsum64(b1);
        if (lane == 0) lgS[lrB] = b1 + biasS1;
      }
    }
    __syncthreads();

    if (t < SEQ && tid < 6){
      float c = sigf(lgB[6+tid])*lcB[tid] + sigf(lgB[tid])*tanhf(lgB[12+tid]);
      lcB[tid] = c;
      h1r[(size_t)((t+1)&3)*HB + 6*w + tid] = sigf(lgB[18+tid])*tanhf(c);
    }
    if (t >= 1 && tid >= 8 && tid < 11){
      int u = tid - 8;
      float c = sigf(lgS[3+u])*lcS[u] + sigf(lgS[u])*tanhf(lgS[6+u]);
      lcS[u] = c;
      h2r[(size_t)(t&3)*HS + 3*w + u] = sigf(lgS[9+u])*tanhf(c);
    }

    ++step;
    gridbar(flags, step, tid, w);
  }

  // ================= Phase Z: zW = d1_Wih @ z + biases (WG-local) =================
  {
#pragma unroll
    for (int k = 0; k < 12; ++k) wS[0][k] = d1Wih[(size_t)RsA*HS + (size_t)k*64 + lane];
    float bz0 = d1bih[RsA] + d1bhh[RsA];
    float bz1 = 0.0f;
    if (wv < 4){
#pragma unroll
      for (int k = 0; k < 12; ++k) wS[1][k] = d1Wih[(size_t)RsB*HS + (size_t)k*64 + lane];
      bz1 = d1bih[RsB] + d1bhh[RsB];
    }
    if (tid < 192)
      ((float4*)lhS)[tid] = ((const float4*)(h2r + (size_t)(SEQ&3)*HS))[tid];  // z
    __syncthreads();
    float zf[12];
#pragma unroll
    for (int k = 0; k < 12; ++k) zf[k] = lhS[k*64 + lane];
    float b0 = 0.f;
#pragma unroll
    for (int k = 0; k < 12; ++k) b0 += wS[0][k]*zf[k];
    b0 = wsum64(b0);
    if (lane == 0) lzw[lrA] = b0 + bz0;
    if (wv < 4){
      float b1 = 0.f;
#pragma unroll
      for (int k = 0; k < 12; ++k) b1 += wS[1][k]*zf[k];
      b1 = wsum64(b1);
      if (lane == 0) lzw[lrB] = b1 + bz1;
    }
    __syncthreads();
  }

  // ---- D-phase weights ----
#pragma unroll
  for (int r = 0; r < 3; ++r){
    const float* src = d2Whh + (size_t)Rb[r]*HB + lane;
#pragma unroll
    for (int k = 0; k < 24; ++k) wR[r][k] = src[(size_t)k*64];
    const float* si = d2Wih + (size_t)Rb[r]*HS + lane;
#pragma unroll
    for (int k = 0; k < 12; ++k) wI[r*12+k] = si[(size_t)k*64];
    biasB[r] = d2bih[Rb[r]] + d2bhh[Rb[r]];
  }
  {
    const float* hA = d1Whh + (size_t)RsA*HS + lane;
#pragma unroll
    for (int k = 0; k < 12; ++k) wS[0][k] = hA[(size_t)k*64];
    if (wv < 4){
      const float* hBp = d1Whh + (size_t)RsB*HS + lane;
#pragma unroll
      for (int k = 0; k < 12; ++k) wS[1][k] = hBp[(size_t)k*64];
    }
  }
  if (tid < 6)              { lowv[tid] = outW[6*w + tid]; lcB[tid] = 0.0f; }
  if (tid >= 8 && tid < 11) lcS[tid-8] = 0.0f;
  const float ob = outb[0];

  // ================= Phase D: d1 step t  ||  d2 step t-1 (+ out dot) =================
  for (int t = 0; t <= SEQ; ++t){
    if (t >= 1 && tid < 384)
      ((float4*)lhB)[tid] = ((const float4*)(hd2r + (size_t)((t-1)&3)*HB))[tid];
    if (tid >= 384){
      int i = tid - 384;
      const float4* s4 = (const float4*)(hd1r + (size_t)(t&3)*HS);
      ((float4*)lhS)[i] = s4[i];
      if (i < 64) ((float4*)lhS)[128+i] = s4[128+i];
    }
    __syncthreads();

    float hS[12];
#pragma unroll
    for (int k = 0; k < 12; ++k) hS[k] = lhS[k*64 + lane];

    if (t < SEQ){   // d1 step t: gates = zW + Whh@hd1[t-1]
      float b0 = 0.f;
#pragma unroll
      for (int k = 0; k < 12; ++k) b0 += wS[0][k]*hS[k];
      b0 = wsum64(b0);
      if (lane == 0) lgS[lrA] = b0 + lzw[lrA];
      if (wv < 4){
        float b1 = 0.f;
#pragma unroll
        for (int k = 0; k < 12; ++k) b1 += wS[1][k]*hS[k];
        b1 = wsum64(b1);
        if (lane == 0) lgS[lrB] = b1 + lzw[lrB];
      }
    }
    if (t >= 1){    // d2 step t-1: gates = Wih@hd1[t-1] + Whh@hd2[t-2] + bias
      float hB[24];
#pragma unroll
      for (int k = 0; k < 24; ++k) hB[k] = lhB[k*64 + lane];
      float a0=0.f, a1=0.f, a2=0.f;
#pragma unroll
      for (int k = 0; k < 24; ++k){
        a0 += wR[0][k]*hB[k];
        a1 += wR[1][k]*hB[k];
        a2 += wR[2][k]*hB[k];
      }
#pragma unroll
      for (int k = 0; k < 12; ++k){
        a0 += wI[0*12+k]*hS[k];
        a1 += wI[1*12+k]*hS[k];
        a2 += wI[2*12+k]*hS[k];
      }
      a0 = wsum64(a0); a1 = wsum64(a1); a2 = wsum64(a2);
      if (lane == 0){
        lgB[3*wv+0] = a0 + biasB[0];
        lgB[3*wv+1] = a1 + biasB[1];
        lgB[3*wv+2] = a2 + biasB[2];
      }
    }
    __syncthreads();

    if (t < SEQ && tid >= 8 && tid < 11){
      int u = tid - 8;
      float c = sigf(lgS[3+u])*lcS[u] + sigf(lgS[u])*tanhf(lgS[6+u]);
      lcS[u] = c;
      hd1r[(size_t)((t+1)&3)*HS + 3*w + u] = sigf(lgS[9+u])*tanhf(c);
    }
    if (t >= 1 && tid < 6){
      float c = sigf(lgB[6+tid])*lcB[tid] + sigf(lgB[tid])*tanhf(lgB[12+tid]);
      lcB[tid] = c;
      float h = sigf(lgB[18+tid])*tanhf(c);
      hd2r[(size_t)(t&3)*HB + 6*w + tid] = h;
      lops[tid] = h * lowv[tid];
    }
    __syncthreads();
    if (t >= 1 && tid == 0)
      outp[(size_t)(t-1)*NWG + w] = lops[0]+lops[1]+lops[2]+lops[3]+lops[4]+lops[5];

    ++step;
    gridbar(flags, step, tid, w);
  }

  // ================= Reduce: out[tau] = sum_w outp[tau][w] + out_b =================
  {
    const int grp = tid >> 5, s5 = tid & 31;
    const int tau = w*16 + grp;
    float s = 0.f;
#pragma unroll
    for (int j = 0; j < 8; ++j) s += outp[(size_t)tau*NWG + s5 + j*32];
#pragma unroll
    for (int m = 16; m > 0; m >>= 1) s += __shfl_xor(s, m);
    if (s5 == 0) out[tau] = s + ob;
  }
}

extern "C" void kernel_launch(void* const* d_in, const int* in_sizes, int n_in,
                              void* d_out, int out_size, void* d_ws, size_t ws_size,
                              hipStream_t stream){
  (void)in_sizes; (void)n_in; (void)out_size; (void)ws_size;
  const float* x     = (const float*)d_in[0];
  const float* e1Wih = (const float*)d_in[1];
  const float* e1Whh = (const float*)d_in[2];
  const float* e1bih = (const float*)d_in[3];
  const float* e1bhh = (const float*)d_in[4];
  const float* e2Wih = (const float*)d_in[5];
  const float* e2Whh = (const float*)d_in[6];
  const float* e2bih = (const float*)d_in[7];
  const float* e2bhh = (const float*)d_in[8];
  const float* d1Wih = (const float*)d_in[9];
  const float* d1Whh = (const float*)d_in[10];
  const float* d1bih = (const float*)d_in[11];
  const float* d1bhh = (const float*)d_in[12];
  const float* d2Wih = (const float*)d_in[13];
  const float* d2Whh = (const float*)d_in[14];
  const float* d2bih = (const float*)d_in[15];
  const float* d2bhh = (const float*)d_in[16];
  const float* outW  = (const float*)d_in[17];
  const float* outb  = (const float*)d_in[18];
  float* out = (float*)d_out;
  float* ws  = (float*)d_ws;

  hipLaunchKernelGGL(init_ws, dim3(32), dim3(256), 0, stream, ws);

  void* args[] = { (void*)&x,
                   (void*)&e1Wih, (void*)&e1Whh, (void*)&e1bih, (void*)&e1bhh,
                   (void*)&e2Wih, (void*)&e2Whh, (void*)&e2bih, (void*)&e2bhh,
                   (void*)&d1Wih, (void*)&d1Whh, (void*)&d1bih, (void*)&d1bhh,
                   (void*)&d2Wih, (void*)&d2Whh, (void*)&d2bih, (void*)&d2bhh,
                   (void*)&outW,  (void*)&outb,  (void*)&out,   (void*)&ws };
  hipLaunchCooperativeKernel((void*)lstm_ae, dim3(NWG), dim3(NTHR), args, 0, stream);
}

// Round 2
// 89388.721 us; speedup vs baseline: 2.1558x; 2.1558x over previous
//
#include <hip/hip_runtime.h>
#include <math.h>
#include <stdint.h>

#define SEQ  4096
#define HB   1536   // big hidden (e1, d2)
#define HS   768    // small hidden (e2, d1)
#define NWG  256
#define NTHR 512

// ws layout in 4-byte units
#define WS_FLAGS 0
#define WS_H1    256
#define WS_H2    (WS_H1  + 4*HB)
#define WS_HD1   (WS_H2  + 4*HS)
#define WS_HD2   (WS_HD1 + 4*HS)
#define WS_OUTP  (WS_HD2 + 4*HB)   // [4096][256] partial sums

__device__ __forceinline__ float sigf(float x){ return 1.0f/(1.0f+expf(-x)); }

__device__ __forceinline__ float wsum64(float v){
#pragma unroll
  for (int m = 32; m > 0; m >>= 1) v += __shfl_xor(v, m);
  return v;
}

// agent-scope (sc1) accessors: bypass non-coherent per-XCD L2, hit LLC
__device__ __forceinline__ float g_load(const float* p){
  return __hip_atomic_load(p, __ATOMIC_RELAXED, __HIP_MEMORY_SCOPE_AGENT);
}
__device__ __forceinline__ void g_store(float* p, float v){
  __hip_atomic_store(p, v, __ATOMIC_RELAXED, __HIP_MEMORY_SCOPE_AGENT);
}

// all waves redundantly scan all 256 per-WG monotonic flags; no barrier inside
__device__ __forceinline__ void pollbar(const int* flags, int target){
  const int b = (threadIdx.x & 63) * 4;
  for(;;){
    int f0 = __hip_atomic_load(&flags[b+0], __ATOMIC_RELAXED, __HIP_MEMORY_SCOPE_AGENT);
    int f1 = __hip_atomic_load(&flags[b+1], __ATOMIC_RELAXED, __HIP_MEMORY_SCOPE_AGENT);
    int f2 = __hip_atomic_load(&flags[b+2], __ATOMIC_RELAXED, __HIP_MEMORY_SCOPE_AGENT);
    int f3 = __hip_atomic_load(&flags[b+3], __ATOMIC_RELAXED, __HIP_MEMORY_SCOPE_AGENT);
    int m = min(min(f0,f1), min(f2,f3));
    if (__all(m >= target)) break;
  }
}

__global__ void init_ws(float* ws){
  int i = threadIdx.x + blockIdx.x*blockDim.x;
  const int n = WS_OUTP;     // flags + all 4 h rings
  for (; i < n; i += blockDim.x*gridDim.x)
    __hip_atomic_store(ws + i, 0.0f, __ATOMIC_RELAXED, __HIP_MEMORY_SCOPE_AGENT);
}

__global__ __launch_bounds__(NTHR, 2) void lstm_ae(
    const float* __restrict__ x,
    const float* __restrict__ e1Wih, const float* __restrict__ e1Whh,
    const float* __restrict__ e1bih, const float* __restrict__ e1bhh,
    const float* __restrict__ e2Wih, const float* __restrict__ e2Whh,
    const float* __restrict__ e2bih, const float* __restrict__ e2bhh,
    const float* __restrict__ d1Wih, const float* __restrict__ d1Whh,
    const float* __restrict__ d1bih, const float* __restrict__ d1bhh,
    const float* __restrict__ d2Wih, const float* __restrict__ d2Whh,
    const float* __restrict__ d2bih, const float* __restrict__ d2bhh,
    const float* __restrict__ outW, const float* __restrict__ outb,
    float* __restrict__ out, float* __restrict__ ws)
{
  const int w    = blockIdx.x;
  const int tid  = threadIdx.x;
  const int lane = tid & 63;
  const int wv   = tid >> 6;          // wave 0..7

  int*   flags = (int*)ws;
  float* h1r  = ws + WS_H1;
  float* h2r  = ws + WS_H2;
  float* hd1r = ws + WS_HD1;
  float* hd2r = ws + WS_HD2;
  float* outp = ws + WS_OUTP;

  __shared__ float lx[SEQ];           // 16 KB: whole input signal
  __shared__ float lhB[HB];           // staged big h (h1 / hd2)
  __shared__ float lhS[HS];           // staged small h (h2 / hd1)
  __shared__ float lgB[24], lgS[12];  // reduced gate pre-activations
  __shared__ float lcB[6],  lcS[3];   // cell states
  __shared__ float lzw[12];

  for (int i = tid; i < SEQ; i += NTHR) lx[i] = x[i];

  // ---- row index mapping ----
  int Rb[3];
#pragma unroll
  for (int r = 0; r < 3; ++r){
    int lr = 3*wv + r;
    Rb[r] = (lr/6)*HB + 6*w + (lr%6);
  }
  const int lrA = wv, lrB = 8 + wv;
  const int RsA = (lrA/3)*HS + 3*w + (lrA%3);
  const int RsB = (lrB/3)*HS + 3*w + (lrB%3);

  // ---- EN-phase weights into registers ----
  float wR[3][24];   // e1_Whh rows                 later: d2_Whh
  float wI[48];      // e2_Wih rows A/B             later: d2_Wih [3][12]
  float wS[2][12];   // e2_Whh rows A/B             later: d1_Wih, then d1_Whh
#pragma unroll
  for (int r = 0; r < 3; ++r){
    const float* src = e1Whh + (size_t)Rb[r]*HB + lane;
#pragma unroll
    for (int k = 0; k < 24; ++k) wR[r][k] = src[(size_t)k*64];
  }
  {
    const float* sA = e2Wih + (size_t)RsA*HB + lane;
#pragma unroll
    for (int k = 0; k < 24; ++k) wI[k] = sA[(size_t)k*64];
    const float* hA = e2Whh + (size_t)RsA*HS + lane;
#pragma unroll
    for (int k = 0; k < 12; ++k) wS[0][k] = hA[(size_t)k*64];
    if (wv < 4){
      const float* sB = e2Wih + (size_t)RsB*HB + lane;
#pragma unroll
      for (int k = 0; k < 24; ++k) wI[24+k] = sB[(size_t)k*64];
      const float* hBp = e2Whh + (size_t)RsB*HS + lane;
#pragma unroll
      for (int k = 0; k < 12; ++k) wS[1][k] = hBp[(size_t)k*64];
    }
  }
  float wihB[3], biasB[3], biasS0, biasS1;
#pragma unroll
  for (int r = 0; r < 3; ++r){
    wihB[r]  = e1Wih[Rb[r]];
    biasB[r] = e1bih[Rb[r]] + e1bhh[Rb[r]];
  }
  biasS0 = e2bih[RsA] + e2bhh[RsA];
  biasS1 = (wv < 4) ? (e2bih[RsB] + e2bhh[RsB]) : 0.0f;

  if (tid < 6)              lcB[tid]   = 0.0f;
  if (tid >= 8 && tid < 11) lcS[tid-8] = 0.0f;

  // ================= Phase EN: e1 step t || e2 step t-1 =================
  // flag value t+1 == "h ring slots for step t+1 published by this WG"
  for (int t = 0; t <= SEQ; ++t){
    pollbar(flags, t);
    if (tid < 384){
      const float* s = h1r + (size_t)(t&3)*HB + tid*4;
      lhB[tid*4+0] = g_load(s+0); lhB[tid*4+1] = g_load(s+1);
      lhB[tid*4+2] = g_load(s+2); lhB[tid*4+3] = g_load(s+3);
    } else if (t >= 1){
      int i = tid - 384;
      const float* s = h2r + (size_t)((t-1)&3)*HS + i*6;
#pragma unroll
      for (int j = 0; j < 6; ++j) lhS[i*6+j] = g_load(s+j);
    }
    __syncthreads();

    float hB[24];
#pragma unroll
    for (int k = 0; k < 24; ++k) hB[k] = lhB[k*64 + lane];

    if (t < SEQ){   // e1 step t
      float a0=0.f, a1=0.f, a2=0.f;
#pragma unroll
      for (int k = 0; k < 24; ++k){
        a0 += wR[0][k]*hB[k];
        a1 += wR[1][k]*hB[k];
        a2 += wR[2][k]*hB[k];
      }
      a0 = wsum64(a0); a1 = wsum64(a1); a2 = wsum64(a2);
      if (lane == 0){
        float xt = lx[t];
        lgB[3*wv+0] = a0 + wihB[0]*xt + biasB[0];
        lgB[3*wv+1] = a1 + wihB[1]*xt + biasB[1];
        lgB[3*wv+2] = a2 + wihB[2]*xt + biasB[2];
      }
    }
    if (t >= 1){    // e2 step t-1
      float hS[12];
#pragma unroll
      for (int k = 0; k < 12; ++k) hS[k] = lhS[k*64 + lane];
      float b0 = 0.f;
#pragma unroll
      for (int k = 0; k < 24; ++k) b0 += wI[k]*hB[k];
#pragma unroll
      for (int k = 0; k < 12; ++k) b0 += wS[0][k]*hS[k];
      b0 = wsum64(b0);
      if (lane == 0) lgS[lrA] = b0 + biasS0;
      if (wv < 4){
        float b1 = 0.f;
#pragma unroll
        for (int k = 0; k < 24; ++k) b1 += wI[24+k]*hB[k];
#pragma unroll
        for (int k = 0; k < 12; ++k) b1 += wS[1][k]*hS[k];
        b1 = wsum64(b1);
        if (lane == 0) lgS[lrB] = b1 + biasS1;
      }
    }
    __syncthreads();

    if (wv == 0){   // all h producers + flag signal live in wave 0
      if (t < SEQ && tid < 6){
        float c = sigf(lgB[6+tid])*lcB[tid] + sigf(lgB[tid])*tanhf(lgB[12+tid]);
        lcB[tid] = c;
        g_store(h1r + (size_t)((t+1)&3)*HB + 6*w + tid, sigf(lgB[18+tid])*tanhf(c));
      }
      if (t >= 1 && tid >= 8 && tid < 11){
        int u = tid - 8;
        float c = sigf(lgS[3+u])*lcS[u] + sigf(lgS[u])*tanhf(lgS[6+u]);
        lcS[u] = c;
        g_store(h2r + (size_t)(t&3)*HS + 3*w + u, sigf(lgS[9+u])*tanhf(c));
      }
      asm volatile("s_waitcnt vmcnt(0)" ::: "memory");
      if (tid == 0)
        __hip_atomic_store(&flags[w], t+1, __ATOMIC_RELAXED, __HIP_MEMORY_SCOPE_AGENT);
    }
  }

  // ================= Phase Z: zW = d1_Wih @ z + biases =================
  const int ZS = SEQ + 1;   // flag value when EN fully complete
  {
#pragma unroll
    for (int k = 0; k < 12; ++k) wS[0][k] = d1Wih[(size_t)RsA*HS + (size_t)k*64 + lane];
    float bz0 = d1bih[RsA] + d1bhh[RsA];
    float bz1 = 0.0f;
    if (wv < 4){
#pragma unroll
      for (int k = 0; k < 12; ++k) wS[1][k] = d1Wih[(size_t)RsB*HS + (size_t)k*64 + lane];
      bz1 = d1bih[RsB] + d1bhh[RsB];
    }
    pollbar(flags, ZS);
    if (tid < 128){
      const float* s = h2r + (size_t)(SEQ&3)*HS + tid*6;
#pragma unroll
      for (int j = 0; j < 6; ++j) lhS[tid*6+j] = g_load(s+j);
    }
    __syncthreads();
    float zf[12];
#pragma unroll
    for (int k = 0; k < 12; ++k) zf[k] = lhS[k*64 + lane];
    float b0 = 0.f;
#pragma unroll
    for (int k = 0; k < 12; ++k) b0 += wS[0][k]*zf[k];
    b0 = wsum64(b0);
    if (lane == 0) lzw[lrA] = b0 + bz0;
    if (wv < 4){
      float b1 = 0.f;
#pragma unroll
      for (int k = 0; k < 12; ++k) b1 += wS[1][k]*zf[k];
      b1 = wsum64(b1);
      if (lane == 0) lzw[lrB] = b1 + bz1;
    }
    __syncthreads();
  }

  // ---- D-phase weights ----
#pragma unroll
  for (int r = 0; r < 3; ++r){
    const float* src = d2Whh + (size_t)Rb[r]*HB + lane;
#pragma unroll
    for (int k = 0; k < 24; ++k) wR[r][k] = src[(size_t)k*64];
    const float* si = d2Wih + (size_t)Rb[r]*HS + lane;
#pragma unroll
    for (int k = 0; k < 12; ++k) wI[r*12+k] = si[(size_t)k*64];
    biasB[r] = d2bih[Rb[r]] + d2bhh[Rb[r]];
  }
  {
    const float* hA = d1Whh + (size_t)RsA*HS + lane;
#pragma unroll
    for (int k = 0; k < 12; ++k) wS[0][k] = hA[(size_t)k*64];
    if (wv < 4){
      const float* hBp = d1Whh + (size_t)RsB*HS + lane;
#pragma unroll
      for (int k = 0; k < 12; ++k) wS[1][k] = hBp[(size_t)k*64];
    }
  }
  float ow = (tid < 6) ? outW[6*w + tid] : 0.0f;
  if (tid < 6)              lcB[tid]   = 0.0f;
  if (tid >= 8 && tid < 11) lcS[tid-8] = 0.0f;
  const float ob = outb[0];

  // ================= Phase D: d1 step t || d2 step t-1 =================
  for (int t = 0; t <= SEQ; ++t){
    pollbar(flags, ZS + t);
    if (t >= 1 && tid < 384){
      const float* s = hd2r + (size_t)((t-1)&3)*HB + tid*4;
      lhB[tid*4+0] = g_load(s+0); lhB[tid*4+1] = g_load(s+1);
      lhB[tid*4+2] = g_load(s+2); lhB[tid*4+3] = g_load(s+3);
    }
    if (tid >= 384){
      int i = tid - 384;
      const float* s = hd1r + (size_t)(t&3)*HS + i*6;
#pragma unroll
      for (int j = 0; j < 6; ++j) lhS[i*6+j] = g_load(s+j);
    }
    __syncthreads();

    float hS[12];
#pragma unroll
    for (int k = 0; k < 12; ++k) hS[k] = lhS[k*64 + lane];

    if (t < SEQ){   // d1 step t
      float b0 = 0.f;
#pragma unroll
      for (int k = 0; k < 12; ++k) b0 += wS[0][k]*hS[k];
      b0 = wsum64(b0);
      if (lane == 0) lgS[lrA] = b0 + lzw[lrA];
      if (wv < 4){
        float b1 = 0.f;
#pragma unroll
        for (int k = 0; k < 12; ++k) b1 += wS[1][k]*hS[k];
        b1 = wsum64(b1);
        if (lane == 0) lgS[lrB] = b1 + lzw[lrB];
      }
    }
    if (t >= 1){    // d2 step t-1
      float hB[24];
#pragma unroll
      for (int k = 0; k < 24; ++k) hB[k] = lhB[k*64 + lane];
      float a0=0.f, a1=0.f, a2=0.f;
#pragma unroll
      for (int k = 0; k < 24; ++k){
        a0 += wR[0][k]*hB[k];
        a1 += wR[1][k]*hB[k];
        a2 += wR[2][k]*hB[k];
      }
#pragma unroll
      for (int k = 0; k < 12; ++k){
        a0 += wI[0*12+k]*hS[k];
        a1 += wI[1*12+k]*hS[k];
        a2 += wI[2*12+k]*hS[k];
      }
      a0 = wsum64(a0); a1 = wsum64(a1); a2 = wsum64(a2);
      if (lane == 0){
        lgB[3*wv+0] = a0 + biasB[0];
        lgB[3*wv+1] = a1 + biasB[1];
        lgB[3*wv+2] = a2 + biasB[2];
      }
    }
    __syncthreads();

    if (wv == 0){
      if (t < SEQ && tid >= 8 && tid < 11){
        int u = tid - 8;
        float c = sigf(lgS[3+u])*lcS[u] + sigf(lgS[u])*tanhf(lgS[6+u]);
        lcS[u] = c;
        g_store(hd1r + (size_t)((t+1)&3)*HS + 3*w + u, sigf(lgS[9+u])*tanhf(c));
      }
      float v = 0.0f;
      if (t >= 1 && tid < 6){
        float c = sigf(lgB[6+tid])*lcB[tid] + sigf(lgB[tid])*tanhf(lgB[12+tid]);
        lcB[tid] = c;
        float h = sigf(lgB[18+tid])*tanhf(c);
        g_store(hd2r + (size_t)(t&3)*HB + 6*w + tid, h);
        v = h * ow;
      }
      if (t >= 1 && tid < 8){
        v += __shfl_xor(v, 1); v += __shfl_xor(v, 2); v += __shfl_xor(v, 4);
        if (tid == 0) g_store(&outp[(size_t)(t-1)*NWG + w], v);
      }
      asm volatile("s_waitcnt vmcnt(0)" ::: "memory");
      if (tid == 0)
        __hip_atomic_store(&flags[w], ZS + t + 1, __ATOMIC_RELAXED, __HIP_MEMORY_SCOPE_AGENT);
    }
  }

  // ================= Reduce: out[tau] = sum_w outp[tau][w] + out_b =================
  pollbar(flags, ZS + SEQ + 1);
  {
    const int grp = tid >> 5, s5 = tid & 31;
    const int tau = w*16 + grp;
    float s = 0.f;
#pragma unroll
    for (int j = 0; j < 8; ++j) s += g_load(&outp[(size_t)tau*NWG + s5 + j*32]);
#pragma unroll
    for (int m = 16; m > 0; m >>= 1) s += __shfl_xor(s, m);
    if (s5 == 0) out[tau] = s + ob;
  }
}

extern "C" void kernel_launch(void* const* d_in, const int* in_sizes, int n_in,
                              void* d_out, int out_size, void* d_ws, size_t ws_size,
                              hipStream_t stream){
  (void)in_sizes; (void)n_in; (void)out_size; (void)ws_size;
  const float* x     = (const float*)d_in[0];
  const float* e1Wih = (const float*)d_in[1];
  const float* e1Whh = (const float*)d_in[2];
  const float* e1bih = (const float*)d_in[3];
  const float* e1bhh = (const float*)d_in[4];
  const float* e2Wih = (const float*)d_in[5];
  const float* e2Whh = (const float*)d_in[6];
  const float* e2bih = (const float*)d_in[7];
  const float* e2bhh = (const float*)d_in[8];
  const float* d1Wih = (const float*)d_in[9];
  const float* d1Whh = (const float*)d_in[10];
  const float* d1bih = (const float*)d_in[11];
  const float* d1bhh = (const float*)d_in[12];
  const float* d2Wih = (const float*)d_in[13];
  const float* d2Whh = (const float*)d_in[14];
  const float* d2bih = (const float*)d_in[15];
  const float* d2bhh = (const float*)d_in[16];
  const float* outW  = (const float*)d_in[17];
  const float* outb  = (const float*)d_in[18];
  float* out = (float*)d_out;
  float* ws  = (float*)d_ws;

  hipLaunchKernelGGL(init_ws, dim3(32), dim3(256), 0, stream, ws);

  void* args[] = { (void*)&x,
                   (void*)&e1Wih, (void*)&e1Whh, (void*)&e1bih, (void*)&e1bhh,
                   (void*)&e2Wih, (void*)&e2Whh, (void*)&e2bih, (void*)&e2bhh,
                   (void*)&d1Wih, (void*)&d1Whh, (void*)&d1bih, (void*)&d1bhh,
                   (void*)&d2Wih, (void*)&d2Whh, (void*)&d2bih, (void*)&d2bhh,
                   (void*)&outW,  (void*)&outb,  (void*)&out,   (void*)&ws };
  hipLaunchCooperativeKernel((void*)lstm_ae, dim3(NWG), dim3(NTHR), args, 0, stream);
}

// Round 3
// 57760.187 us; speedup vs baseline: 3.3362x; 1.5476x over previous
//
#include <hip/hip_runtime.h>
#include <math.h>
#include <stdint.h>

#define SEQ   4096
#define HBD   1536   // big hidden (e1, d2)
#define HSD   768    // small hidden (e2, d1)
#define NWG   256
#define NTHR  512
#define ZBASE (SEQ+1)

// ws layout (floats): packets [4 slots][256 wg][16 floats], then outp [4096][256]
#define WS_PK   0
#define WS_OUTP (4*NWG*16)

typedef float f32x4 __attribute__((ext_vector_type(4)));

__device__ __forceinline__ float sigf(float x){ return 1.0f/(1.0f+expf(-x)); }

__device__ __forceinline__ float wsum64(float v){
#pragma unroll
  for (int m = 32; m > 0; m >>= 1) v += __shfl_xor(v, m);
  return v;
}

__device__ __forceinline__ float g_load(const float* p){
  return __hip_atomic_load(p, __ATOMIC_RELAXED, __HIP_MEMORY_SCOPE_AGENT);
}
__device__ __forceinline__ void g_store(float* p, float v){
  __hip_atomic_store(p, v, __ATOMIC_RELAXED, __HIP_MEMORY_SCOPE_AGENT);
}

// wave polls counters of all 256 packet lines of slot `sb`; own WG skipped
__device__ __forceinline__ void pollwave(const float* sb, int target, int w, int lane){
  const int* cnt = (const int*)sb + 15;
  for(;;){
    int ok = 1;
#pragma unroll
    for (int m = 0; m < 4; ++m){
      const int line = 64*m + lane;
      int c = (line == w) ? target
            : __hip_atomic_load(cnt + (size_t)line*16, __ATOMIC_RELAXED, __HIP_MEMORY_SCOPE_AGENT);
      ok &= (c >= target);
    }
    if (__all(ok)) break;
  }
}

// 12 coherent loads (bypass L2 via sc0 sc1) + waitcnt inside one asm block.
// A[m]=floats0-3, B[m]=floats4-7, C[m]=float8 of line (64m+lane).
#define LOADPKT(sbase)                                                       \
  {                                                                          \
    const float* p0_ = (sbase) + (size_t)(lane)*16;                          \
    const float* p1_ = (sbase) + (size_t)(64+lane)*16;                       \
    const float* p2_ = (sbase) + (size_t)(128+lane)*16;                      \
    const float* p3_ = (sbase) + (size_t)(192+lane)*16;                      \
    asm volatile(                                                            \
      "global_load_dwordx4 %0, %12, off sc0 sc1\n\t"                         \
      "global_load_dwordx4 %1, %12, off offset:16 sc0 sc1\n\t"               \
      "global_load_dword   %2, %12, off offset:32 sc0 sc1\n\t"               \
      "global_load_dwordx4 %3, %13, off sc0 sc1\n\t"                         \
      "global_load_dwordx4 %4, %13, off offset:16 sc0 sc1\n\t"               \
      "global_load_dword   %5, %13, off offset:32 sc0 sc1\n\t"               \
      "global_load_dwordx4 %6, %14, off sc0 sc1\n\t"                         \
      "global_load_dwordx4 %7, %14, off offset:16 sc0 sc1\n\t"               \
      "global_load_dword   %8, %14, off offset:32 sc0 sc1\n\t"               \
      "global_load_dwordx4 %9, %15, off sc0 sc1\n\t"                         \
      "global_load_dwordx4 %10, %15, off offset:16 sc0 sc1\n\t"              \
      "global_load_dword   %11, %15, off offset:32 sc0 sc1\n\t"              \
      "s_waitcnt vmcnt(0)"                                                   \
      : "=&v"(A[0]), "=&v"(B[0]), "=&v"(C[0]),                               \
        "=&v"(A[1]), "=&v"(B[1]), "=&v"(C[1]),                               \
        "=&v"(A[2]), "=&v"(B[2]), "=&v"(C[2]),                               \
        "=&v"(A[3]), "=&v"(B[3]), "=&v"(C[3])                                \
      : "v"(p0_), "v"(p1_), "v"(p2_), "v"(p3_)                               \
      : "memory");                                                           \
  }

__global__ void init_ws(float* ws){
  int i = threadIdx.x + blockIdx.x*blockDim.x;
  for (; i < WS_PK + 4*NWG*16; i += blockDim.x*gridDim.x)
    __hip_atomic_store(ws + i, 0.0f, __ATOMIC_RELAXED, __HIP_MEMORY_SCOPE_AGENT);
}

__global__ __launch_bounds__(NTHR, 1) void lstm_ae(
    const float* __restrict__ x,
    const float* __restrict__ e1Wih, const float* __restrict__ e1Whh,
    const float* __restrict__ e1bih, const float* __restrict__ e1bhh,
    const float* __restrict__ e2Wih, const float* __restrict__ e2Whh,
    const float* __restrict__ e2bih, const float* __restrict__ e2bhh,
    const float* __restrict__ d1Wih, const float* __restrict__ d1Whh,
    const float* __restrict__ d1bih, const float* __restrict__ d1bhh,
    const float* __restrict__ d2Wih, const float* __restrict__ d2Whh,
    const float* __restrict__ d2bih, const float* __restrict__ d2bhh,
    const float* __restrict__ outW, const float* __restrict__ outb,
    float* __restrict__ out, float* __restrict__ ws)
{
  const int w    = blockIdx.x;
  const int tid  = threadIdx.x;
  const int lane = tid & 63;
  const int wv   = tid >> 6;

  float* pk   = ws + WS_PK;
  float* outp = ws + WS_OUTP;

  __shared__ float lx[SEQ];           // 16 KB input signal
  __shared__ float lgB[24], lgS[12];  // gate pre-activations
  __shared__ float lzw[12];

  for (int i = tid; i < SEQ; i += NTHR) lx[i] = x[i];

  // ---- row mapping (same as before) ----
  int Rb[3];
#pragma unroll
  for (int r = 0; r < 3; ++r){
    int lr = 3*wv + r;
    Rb[r] = (lr/6)*HBD + 6*w + (lr%6);
  }
  const int lrA = wv, lrB = 8 + wv;
  const int RsA = (lrA/3)*HSD + 3*w + (lrA%3);
  const int RsB = (lrB/3)*HSD + 3*w + (lrB%3);

  // ---- EN weights, packet-fragment layout ----
  // big K=1536: frag[m*6+j] multiplies h[6*(64m+lane)+j]  -> W row + 384m + 6*lane + j
  // small K=768: frag[m*3+j] multiplies h[3*(64m+lane)+j] -> W row + 192m + 3*lane + j
  float wR[3][24];   // e1_Whh / d2_Whh
  float wI[48];      // e2_Wih A/B  /  d2_Wih [3][12]
  float wS[2][12];   // e2_Whh A/B  /  d1_Wih  /  d1_Whh
#pragma unroll
  for (int r = 0; r < 3; ++r){
    const float* src = e1Whh + (size_t)Rb[r]*HBD + 6*lane;
#pragma unroll
    for (int m = 0; m < 4; ++m)
#pragma unroll
      for (int j = 0; j < 6; ++j) wR[r][m*6+j] = src[384*m + j];
  }
  {
    const float* sA = e2Wih + (size_t)RsA*HBD + 6*lane;
#pragma unroll
    for (int m = 0; m < 4; ++m)
#pragma unroll
      for (int j = 0; j < 6; ++j) wI[m*6+j] = sA[384*m + j];
    const float* hA = e2Whh + (size_t)RsA*HSD + 3*lane;
#pragma unroll
    for (int m = 0; m < 4; ++m)
#pragma unroll
      for (int j = 0; j < 3; ++j) wS[0][m*3+j] = hA[192*m + j];
    if (wv < 4){
      const float* sB = e2Wih + (size_t)RsB*HBD + 6*lane;
#pragma unroll
      for (int m = 0; m < 4; ++m)
#pragma unroll
        for (int j = 0; j < 6; ++j) wI[24+m*6+j] = sB[384*m + j];
      const float* hB2 = e2Whh + (size_t)RsB*HSD + 3*lane;
#pragma unroll
      for (int m = 0; m < 4; ++m)
#pragma unroll
        for (int j = 0; j < 3; ++j) wS[1][m*3+j] = hB2[192*m + j];
    }
  }
  float wihB[3], biasB[3], biasS0, biasS1;
#pragma unroll
  for (int r = 0; r < 3; ++r){
    wihB[r]  = e1Wih[Rb[r]];
    biasB[r] = e1bih[Rb[r]] + e1bhh[Rb[r]];
  }
  biasS0 = e2bih[RsA] + e2bhh[RsA];
  biasS1 = (wv < 4) ? (e2bih[RsB] + e2bhh[RsB]) : 0.0f;

  float cB = 0.0f, cS = 0.0f;   // cell states: wave0 lanes 0-5 (big), 8-10 (small)

  // ================= Phase EN: iter g: e1 time g || e2 time g-1 =================
  for (int g = 0; g <= SEQ; ++g){
    float* sb = pk + (size_t)(g&3)*NWG*16;
    if (wv == 1) pollwave(sb, g, w, lane);
    __syncthreads();                      // S1

    f32x4 A[4], B[4]; float C[4];
    LOADPKT(sb);

    if (g < SEQ){   // e1: 3 big rows
      float a0=0.f, a1=0.f, a2=0.f;
#pragma unroll
      for (int m = 0; m < 4; ++m){
        float h0=A[m][0],h1=A[m][1],h2=A[m][2],h3=A[m][3],h4=B[m][0],h5=B[m][1];
        a0 += wR[0][m*6+0]*h0 + wR[0][m*6+1]*h1 + wR[0][m*6+2]*h2
            + wR[0][m*6+3]*h3 + wR[0][m*6+4]*h4 + wR[0][m*6+5]*h5;
        a1 += wR[1][m*6+0]*h0 + wR[1][m*6+1]*h1 + wR[1][m*6+2]*h2
            + wR[1][m*6+3]*h3 + wR[1][m*6+4]*h4 + wR[1][m*6+5]*h5;
        a2 += wR[2][m*6+0]*h0 + wR[2][m*6+1]*h1 + wR[2][m*6+2]*h2
            + wR[2][m*6+3]*h3 + wR[2][m*6+4]*h4 + wR[2][m*6+5]*h5;
      }
      a0 = wsum64(a0); a1 = wsum64(a1); a2 = wsum64(a2);
      if (lane == 0){
        float xt = lx[g];
        lgB[3*wv+0] = a0 + wihB[0]*xt + biasB[0];
        lgB[3*wv+1] = a1 + wihB[1]*xt + biasB[1];
        lgB[3*wv+2] = a2 + wihB[2]*xt + biasB[2];
      }
    }
    if (g >= 1){    // e2: rows lrA (all waves), lrB (wv<4)
      float b0 = 0.f;
#pragma unroll
      for (int m = 0; m < 4; ++m){
        b0 += wI[m*6+0]*A[m][0] + wI[m*6+1]*A[m][1] + wI[m*6+2]*A[m][2]
            + wI[m*6+3]*A[m][3] + wI[m*6+4]*B[m][0] + wI[m*6+5]*B[m][1];
        b0 += wS[0][m*3+0]*B[m][2] + wS[0][m*3+1]*B[m][3] + wS[0][m*3+2]*C[m];
      }
      b0 = wsum64(b0);
      if (lane == 0) lgS[lrA] = b0 + biasS0;
      if (wv < 4){
        float b1 = 0.f;
#pragma unroll
        for (int m = 0; m < 4; ++m){
          b1 += wI[24+m*6+0]*A[m][0] + wI[24+m*6+1]*A[m][1] + wI[24+m*6+2]*A[m][2]
              + wI[24+m*6+3]*A[m][3] + wI[24+m*6+4]*B[m][0] + wI[24+m*6+5]*B[m][1];
          b1 += wS[1][m*3+0]*B[m][2] + wS[1][m*3+1]*B[m][3] + wS[1][m*3+2]*C[m];
        }
        b1 = wsum64(b1);
        if (lane == 0) lgS[lrB] = b1 + biasS1;
      }
    }
    __syncthreads();                      // S2

    if (wv == 0){   // produce packet g+1: {h1[g+1], h2[g], counter g+1}
      float* nxt = pk + (size_t)((g+1)&3)*NWG*16 + (size_t)w*16;
      if (g < SEQ && lane < 6){
        float gi = lgB[lane], gf = lgB[6+lane], gg = lgB[12+lane], go = lgB[18+lane];
        cB = sigf(gf)*cB + sigf(gi)*tanhf(gg);
        g_store(nxt + lane, sigf(go)*tanhf(cB));
      }
      if (g >= 1 && lane >= 8 && lane < 11){
        int u = lane - 8;
        float gi = lgS[u], gf = lgS[3+u], gg = lgS[6+u], go = lgS[9+u];
        cS = sigf(gf)*cS + sigf(gi)*tanhf(gg);
        g_store(nxt + 6 + u, sigf(go)*tanhf(cS));
      }
      asm volatile("s_waitcnt vmcnt(0)" ::: "memory");
      if (lane == 0)
        __hip_atomic_store((int*)nxt + 15, g+1, __ATOMIC_RELAXED, __HIP_MEMORY_SCOPE_AGENT);
    }
  }

  // ================= Phase Z: zW = d1_Wih @ z + biases =================
  {
#pragma unroll
    for (int m = 0; m < 4; ++m)
#pragma unroll
      for (int j = 0; j < 3; ++j)
        wS[0][m*3+j] = d1Wih[(size_t)RsA*HSD + 3*lane + 192*m + j];
    float bz0 = d1bih[RsA] + d1bhh[RsA];
    float bz1 = 0.0f;
    if (wv < 4){
#pragma unroll
      for (int m = 0; m < 4; ++m)
#pragma unroll
        for (int j = 0; j < 3; ++j)
          wS[1][m*3+j] = d1Wih[(size_t)RsB*HSD + 3*lane + 192*m + j];
      bz1 = d1bih[RsB] + d1bhh[RsB];
    }
    float* sb = pk + (size_t)(ZBASE&3)*NWG*16;
    if (wv == 1) pollwave(sb, ZBASE, w, lane);
    __syncthreads();
    f32x4 A[4], B[4]; float C[4];
    LOADPKT(sb);                       // small part = z
    float b0 = 0.f;
#pragma unroll
    for (int m = 0; m < 4; ++m)
      b0 += wS[0][m*3+0]*B[m][2] + wS[0][m*3+1]*B[m][3] + wS[0][m*3+2]*C[m];
    b0 = wsum64(b0);
    if (lane == 0) lzw[lrA] = b0 + bz0;
    if (wv < 4){
      float b1 = 0.f;
#pragma unroll
      for (int m = 0; m < 4; ++m)
        b1 += wS[1][m*3+0]*B[m][2] + wS[1][m*3+1]*B[m][3] + wS[1][m*3+2]*C[m];
      b1 = wsum64(b1);
      if (lane == 0) lzw[lrB] = b1 + bz1;
    }
    __syncthreads();
  }

  // ---- D-phase weights ----
#pragma unroll
  for (int r = 0; r < 3; ++r){
    const float* src = d2Whh + (size_t)Rb[r]*HBD + 6*lane;
#pragma unroll
    for (int m = 0; m < 4; ++m)
#pragma unroll
      for (int j = 0; j < 6; ++j) wR[r][m*6+j] = src[384*m + j];
    const float* si = d2Wih + (size_t)Rb[r]*HSD + 3*lane;
#pragma unroll
    for (int m = 0; m < 4; ++m)
#pragma unroll
      for (int j = 0; j < 3; ++j) wI[r*12+m*3+j] = si[192*m + j];
    biasB[r] = d2bih[Rb[r]] + d2bhh[Rb[r]];
  }
  {
    const float* hA = d1Whh + (size_t)RsA*HSD + 3*lane;
#pragma unroll
    for (int m = 0; m < 4; ++m)
#pragma unroll
      for (int j = 0; j < 3; ++j) wS[0][m*3+j] = hA[192*m + j];
    if (wv < 4){
      const float* hB2 = d1Whh + (size_t)RsB*HSD + 3*lane;
#pragma unroll
      for (int m = 0; m < 4; ++m)
#pragma unroll
        for (int j = 0; j < 3; ++j) wS[1][m*3+j] = hB2[192*m + j];
    }
  }
  float ow = 0.0f;
  if (wv == 0 && lane < 6) ow = outW[6*w + lane];
  cB = 0.0f; cS = 0.0f;
  const float ob = outb[0];

  // ================= Phase D: iter t: d1 time t || d2 time t-1 =================
  for (int t = 0; t <= SEQ; ++t){
    float* sb = pk + (size_t)((ZBASE+t)&3)*NWG*16;
    if (t >= 1 && wv == 1) pollwave(sb, ZBASE+t, w, lane);
    __syncthreads();                      // S1

    f32x4 A[4], B[4]; float C[4];
    if (t >= 1){ LOADPKT(sb); }
    else {
#pragma unroll
      for (int m = 0; m < 4; ++m){ A[m] = (f32x4)0.0f; B[m] = (f32x4)0.0f; C[m] = 0.0f; }
    }

    if (t < SEQ){   // d1: gates = zW + Whh@hd1[t]
      float b0 = 0.f;
#pragma unroll
      for (int m = 0; m < 4; ++m)
        b0 += wS[0][m*3+0]*B[m][2] + wS[0][m*3+1]*B[m][3] + wS[0][m*3+2]*C[m];
      b0 = wsum64(b0);
      if (lane == 0) lgS[lrA] = b0 + lzw[lrA];
      if (wv < 4){
        float b1 = 0.f;
#pragma unroll
        for (int m = 0; m < 4; ++m)
          b1 += wS[1][m*3+0]*B[m][2] + wS[1][m*3+1]*B[m][3] + wS[1][m*3+2]*C[m];
        b1 = wsum64(b1);
        if (lane == 0) lgS[lrB] = b1 + lzw[lrB];
      }
    }
    if (t >= 1){    // d2: 3 big rows, inputs hd1[t] (small) + state hd2[t-1] (big)
      float a0=0.f, a1=0.f, a2=0.f;
#pragma unroll
      for (int m = 0; m < 4; ++m){
        float h0=A[m][0],h1=A[m][1],h2=A[m][2],h3=A[m][3],h4=B[m][0],h5=B[m][1];
        a0 += wR[0][m*6+0]*h0 + wR[0][m*6+1]*h1 + wR[0][m*6+2]*h2
            + wR[0][m*6+3]*h3 + wR[0][m*6+4]*h4 + wR[0][m*6+5]*h5;
        a1 += wR[1][m*6+0]*h0 + wR[1][m*6+1]*h1 + wR[1][m*6+2]*h2
            + wR[1][m*6+3]*h3 + wR[1][m*6+4]*h4 + wR[1][m*6+5]*h5;
        a2 += wR[2][m*6+0]*h0 + wR[2][m*6+1]*h1 + wR[2][m*6+2]*h2
            + wR[2][m*6+3]*h3 + wR[2][m*6+4]*h4 + wR[2][m*6+5]*h5;
        float s0=B[m][2], s1=B[m][3], s2=C[m];
        a0 += wI[0*12+m*3+0]*s0 + wI[0*12+m*3+1]*s1 + wI[0*12+m*3+2]*s2;
        a1 += wI[1*12+m*3+0]*s0 + wI[1*12+m*3+1]*s1 + wI[1*12+m*3+2]*s2;
        a2 += wI[2*12+m*3+0]*s0 + wI[2*12+m*3+1]*s1 + wI[2*12+m*3+2]*s2;
      }
      a0 = wsum64(a0); a1 = wsum64(a1); a2 = wsum64(a2);
      if (lane == 0){
        lgB[3*wv+0] = a0 + biasB[0];
        lgB[3*wv+1] = a1 + biasB[1];
        lgB[3*wv+2] = a2 + biasB[2];
      }
    }
    __syncthreads();                      // S2

    if (wv == 0){   // produce packet ZBASE+t+1: {hd2[t], hd1[t+1], counter}
      float* nxt = pk + (size_t)((ZBASE+t+1)&3)*NWG*16 + (size_t)w*16;
      if (t < SEQ && lane >= 8 && lane < 11){
        int u = lane - 8;
        float gi = lgS[u], gf = lgS[3+u], gg = lgS[6+u], go = lgS[9+u];
        cS = sigf(gf)*cS + sigf(gi)*tanhf(gg);
        g_store(nxt + 6 + u, sigf(go)*tanhf(cS));
      }
      float v = 0.0f;
      if (t == 0 && lane < 6) g_store(nxt + lane, 0.0f);  // hd2[0] = 0 (slot holds stale EN data)
      if (t >= 1 && lane < 6){
        float gi = lgB[lane], gf = lgB[6+lane], gg = lgB[12+lane], go = lgB[18+lane];
        cB = sigf(gf)*cB + sigf(gi)*tanhf(gg);
        float h = sigf(go)*tanhf(cB);
        g_store(nxt + lane, h);
        v = h * ow;
      }
      if (t >= 1 && lane < 8){
        v += __shfl_xor(v, 1); v += __shfl_xor(v, 2); v += __shfl_xor(v, 4);
        if (lane == 0) g_store(&outp[(size_t)(t-1)*NWG + w], v);
      }
      asm volatile("s_waitcnt vmcnt(0)" ::: "memory");
      if (lane == 0)
        __hip_atomic_store((int*)nxt + 15, ZBASE+t+1, __ATOMIC_RELAXED, __HIP_MEMORY_SCOPE_AGENT);
    }
  }

  // ================= Reduce: out[tau] = sum_w outp[tau][w] + out_b =================
  {
    float* sb = pk + (size_t)((ZBASE+SEQ+1)&3)*NWG*16;
    if (wv == 1) pollwave(sb, ZBASE+SEQ+1, w, lane);
    __syncthreads();
    const int grp = tid >> 5, s5 = tid & 31;
    const int tau = w*16 + grp;
    float s = 0.f;
#pragma unroll
    for (int j = 0; j < 8; ++j) s += g_load(&outp[(size_t)tau*NWG + s5 + j*32]);
#pragma unroll
    for (int m = 16; m > 0; m >>= 1) s += __shfl_xor(s, m);
    if (s5 == 0) out[tau] = s + ob;
  }
}

extern "C" void kernel_launch(void* const* d_in, const int* in_sizes, int n_in,
                              void* d_out, int out_size, void* d_ws, size_t ws_size,
                              hipStream_t stream){
  (void)in_sizes; (void)n_in; (void)out_size; (void)ws_size;
  const float* x     = (const float*)d_in[0];
  const float* e1Wih = (const float*)d_in[1];
  const float* e1Whh = (const float*)d_in[2];
  const float* e1bih = (const float*)d_in[3];
  const float* e1bhh = (const float*)d_in[4];
  const float* e2Wih = (const float*)d_in[5];
  const float* e2Whh = (const float*)d_in[6];
  const float* e2bih = (const float*)d_in[7];
  const float* e2bhh = (const float*)d_in[8];
  const float* d1Wih = (const float*)d_in[9];
  const float* d1Whh = (const float*)d_in[10];
  const float* d1bih = (const float*)d_in[11];
  const float* d1bhh = (const float*)d_in[12];
  const float* d2Wih = (const float*)d_in[13];
  const float* d2Whh = (const float*)d_in[14];
  const float* d2bih = (const float*)d_in[15];
  const float* d2bhh = (const float*)d_in[16];
  const float* outW  = (const float*)d_in[17];
  const float* outb  = (const float*)d_in[18];
  float* out = (float*)d_out;
  float* ws  = (float*)d_ws;

  hipLaunchKernelGGL(init_ws, dim3(32), dim3(256), 0, stream, ws);

  void* args[] = { (void*)&x,
                   (void*)&e1Wih, (void*)&e1Whh, (void*)&e1bih, (void*)&e1bhh,
                   (void*)&e2Wih, (void*)&e2Whh, (void*)&e2bih, (void*)&e2bhh,
                   (void*)&d1Wih, (void*)&d1Whh, (void*)&d1bih, (void*)&d1bhh,
                   (void*)&d2Wih, (void*)&d2Whh, (void*)&d2bih, (void*)&d2bhh,
                   (void*)&outW,  (void*)&outb,  (void*)&out,   (void*)&ws };
  hipLaunchCooperativeKernel((void*)lstm_ae, dim3(NWG), dim3(NTHR), args, 0, stream);
}